// Round 9
// baseline (637.275 us; speedup 1.0000x reference)
//
#include <hip/hip_runtime.h>

// Problem constants
#define DIM_   512
#define NSEQ   1024
#define BB     16
#define HH     16
#define KD_    32
#define DD_    128
#define LDQKV  3072   // H*(2*KD+D)
#define DH_    2048   // H*D
#define SCALE_ 0.17677669529663687f  // 32^-0.5
#define SCALE2_ (0.17677669529663687f * 1.4426950408889634f)  // SCALE * log2(e)

typedef __bf16 bf16x8 __attribute__((ext_vector_type(8)));
typedef float  f32x4  __attribute__((ext_vector_type(4)));

typedef __attribute__((address_space(1))) const unsigned int guint;
typedef __attribute__((address_space(3))) unsigned int luint;
#define GLL16(gp, lp) __builtin_amdgcn_global_load_lds((guint*)(gp), (luint*)(lp), 16, 0, 0)

static __device__ __forceinline__ unsigned short f2bf(float f) {
  unsigned int u = __builtin_bit_cast(unsigned int, f);
  u += 0x7fffu + ((u >> 16) & 1u);   // round-to-nearest-even
  return (unsigned short)(u >> 16);
}
// key-within-group permutation (R5/R6 HW-verified), matched in p_sm + PV reads.
#define SGM(t) ((((t) & 3) << 1) | (((t) >> 2) & 1))

// ---------------- fp32 -> bf16 convert ----------------
__global__ __launch_bounds__(256) void cvt_kernel(const float* __restrict__ in,
                                                  unsigned short* __restrict__ out,
                                                  int n) {
  int i = blockIdx.x * 256 + threadIdx.x;
  if (i < n) out[i] = f2bf(in[i]);
}

// ---------------- LayerNorm (fp32 in) -> bf16 out ----------------
__global__ __launch_bounds__(256) void ln_kernel(const float* __restrict__ x,
                                                 const float* __restrict__ gamma,
                                                 const float* __restrict__ beta,
                                                 unsigned short* __restrict__ xn) {
  int row = blockIdx.x, t = threadIdx.x;
  const float* xr = x + (size_t)row * DIM_;
  float2 v = *(const float2*)(xr + t * 2);
  float s = v.x + v.y, sq = v.x * v.x + v.y * v.y;
#pragma unroll
  for (int off = 32; off; off >>= 1) {
    s  += __shfl_xor(s, off, 64);
    sq += __shfl_xor(sq, off, 64);
  }
  __shared__ float red[8];
  int wid = t >> 6, lane = t & 63;
  if (lane == 0) { red[wid * 2] = s; red[wid * 2 + 1] = sq; }
  __syncthreads();
  float S  = red[0] + red[2] + red[4] + red[6];
  float SQ = red[1] + red[3] + red[5] + red[7];
  float mu   = S * (1.f / DIM_);
  float var  = SQ * (1.f / DIM_) - mu * mu;
  float rstd = rsqrtf(var + 1e-5f);
  int c = t * 2;
  xn[(size_t)row * DIM_ + c]     = f2bf((v.x - mu) * rstd * gamma[c]     + beta[c]);
  xn[(size_t)row * DIM_ + c + 1] = f2bf((v.y - mu) * rstd * gamma[c + 1] + beta[c + 1]);
}

// ---------------- GEMM (GLL staging, bf16/fp32 out): C = A*W^T + bias ----------------
template <typename OUT>
__global__ __launch_bounds__(256) void gemm_gll(const unsigned short* __restrict__ A, int lda,
                                                const unsigned short* __restrict__ W, int ldb,
                                                const float* __restrict__ bias,
                                                OUT* __restrict__ C, int ldc,
                                                int K) {
  __shared__ unsigned short a_sm[128][64];
  __shared__ unsigned short b_sm[128][64];
  int tid = threadIdx.x;
  int lane = tid & 63, w = tid >> 6;
  int quad = lane >> 4, l15 = lane & 15;
  int wr = w >> 1, wc = w & 1;
  long tm = (long)blockIdx.y * 128, tn = (long)blockIdx.x * 128;
  int srow = w * 8 + (lane >> 3), scol = (lane & 7) * 8;

  f32x4 acc[4][4] = {};

  for (int k0 = 0; k0 < K; k0 += 64) {
    __syncthreads();
#pragma unroll
    for (int it = 0; it < 4; it++) {
      GLL16(A + (tm + it * 32 + srow) * lda + k0 + scol, &a_sm[it * 32 + w * 8][0]);
      GLL16(W + (tn + it * 32 + srow) * ldb + k0 + scol, &b_sm[it * 32 + w * 8][0]);
    }
    __syncthreads();
#pragma unroll
    for (int kk = 0; kk < 64; kk += 32) {
      bf16x8 af[4], bfr[4];
#pragma unroll
      for (int i = 0; i < 4; i++)
        af[i] = *(const bf16x8*)&a_sm[wr * 64 + i * 16 + l15][kk + quad * 8];
#pragma unroll
      for (int j = 0; j < 4; j++)
        bfr[j] = *(const bf16x8*)&b_sm[wc * 64 + j * 16 + l15][kk + quad * 8];
#pragma unroll
      for (int i = 0; i < 4; i++)
#pragma unroll
        for (int j = 0; j < 4; j++)
          acc[i][j] = __builtin_amdgcn_mfma_f32_16x16x32_bf16(af[i], bfr[j], acc[i][j], 0, 0, 0);
    }
  }
#pragma unroll
  for (int j = 0; j < 4; j++) {
    long col = tn + wc * 64 + j * 16 + l15;
    float bv = bias[col];
#pragma unroll
    for (int i = 0; i < 4; i++) {
      long row0 = tm + wr * 64 + i * 16 + quad * 4;
#pragma unroll
      for (int r = 0; r < 4; r++) {
        float val = acc[i][j][r] + bv;
        if constexpr (__is_same(OUT, float))
          C[(row0 + r) * ldc + col] = val;
        else
          C[(row0 + r) * ldc + col] = f2bf(val);
      }
    }
  }
}

// ---------------- Flash attention v6: 128-row q-tile, XCD-local bh grid --------------
// grid (bh=256, qb=8): linear id = bh + 256*qb = bh (mod 8) -> all qb-tiles of a
// (b,h) land on one XCD -> K/V served from that XCD's L2.
// Wave w computes S rows w*32..w*32+32 (p-groups 2w,2w+1); PV wave (wq=w&1, wd=w>>1)
// covers p-groups 4wq..4wq+3 x d-blocks 4wd..4wd+3.
__global__ __launch_bounds__(256, 3) void attn_kernel(const unsigned short* __restrict__ qkv,
                                                      const float* __restrict__ ab,
                                                      unsigned short* __restrict__ attn_out) {
  __shared__ float lut[1024];
  __shared__ unsigned short vt[128][72];      // V^T tile, SGM-swizzled cols
  __shared__ unsigned short k_sm[64][40];
  __shared__ unsigned short p_sm[8][16][68];  // stride 34 dw: 32-bank 2-way writes
  __shared__ float l_sm[128];

  int tid = threadIdx.x;
  int lane = tid & 63, w = tid >> 6;
  int quad = lane >> 4, l15 = lane & 15;
  int wq = w & 1, wd = w >> 1;
  int bh = blockIdx.x;
  int qb = blockIdx.y;
  int b = bh >> 4, h = bh & 15;
  const unsigned short* base = qkv + (size_t)b * NSEQ * LDQKV + h * 192;

  for (int t = tid; t < 1024; t += 256) lut[t] = ab[h * 1024 + t] * 1.4426950408889634f;

  // Q fragments: 2 groups of 16 rows per wave
  bf16x8 qf[2];
#pragma unroll
  for (int g = 0; g < 2; g++)
    qf[g] = *(const bf16x8*)(base + (size_t)(qb * 128 + w * 32 + g * 16 + l15) * LDQKV + quad * 8);

  f32x4 accO[4][4] = {};
  float l_r[2][4] = {};

  int pcol_lo = (l15 & 8) | SGM(l15 & 7);
  int kkey = tid >> 2, kch = tid & 3;

  // prologue prefetch (tile 0)
  uint4 vreg[4];
  uint4 kreg;
#pragma unroll
  for (int i = 0; i < 4; i++) {
    int c = tid + i * 256;
    int m = c >> 4, c8 = c & 15;
    vreg[i] = *(const uint4*)(base + (size_t)m * LDQKV + 64 + c8 * 8);
  }
  kreg = *(const uint4*)(base + (size_t)kkey * LDQKV + 32 + kch * 8);

  for (int kt = 0; kt < 16; kt++) {
    __syncthreads();  // prior tile's readers done
    // stage regs -> LDS (SGM scatter for V^T)
#pragma unroll
    for (int i = 0; i < 4; i++) {
      int c = tid + i * 256;
      int m = c >> 4, c8 = c & 15;
      const unsigned short* pv = (const unsigned short*)&vreg[i];
      int col = (((m >> 3) ^ (c8 & 7)) << 3) | SGM(m & 7);
#pragma unroll
      for (int e = 0; e < 8; e++) vt[c8 * 8 + e][col] = pv[e];
    }
    *(uint4*)&k_sm[kkey][kch * 8] = kreg;
    __syncthreads();  // staged

    if (kt < 15) {
#pragma unroll
      for (int i = 0; i < 4; i++) {
        int c = tid + i * 256;
        int m = c >> 4, c8 = c & 15;
        vreg[i] = *(const uint4*)(base + (size_t)((kt + 1) * 64 + m) * LDQKV + 64 + c8 * 8);
      }
      kreg = *(const uint4*)(base + (size_t)((kt + 1) * 64 + kkey) * LDQKV + 32 + kch * 8);
    }

    // S = Q K^T for both q-groups (K frags reused across groups)
    f32x4 s[2][4];
#pragma unroll
    for (int nb = 0; nb < 4; nb++) {
      bf16x8 kf = *(const bf16x8*)&k_sm[nb * 16 + l15][quad * 8];
      f32x4 z = {};
#pragma unroll
      for (int g = 0; g < 2; g++)
        s[g][nb] = __builtin_amdgcn_mfma_f32_16x16x32_bf16(qf[g], kf, z, 0, 0, 0);
    }

    // scale + analytic bias + exp2; l partials; write P (SGM-permuted cols)
#pragma unroll
    for (int g = 0; g < 2; g++) {
#pragma unroll
      for (int nb = 0; nb < 4; nb++) {
        int cc = kt * 64 + nb * 16 + l15;
        int cx = cc >> 5, cy = cc & 31;
#pragma unroll
        for (int r = 0; r < 4; r++) {
          int rr = qb * 128 + w * 32 + g * 16 + quad * 4 + r;
          int dx = (rr >> 5) - cx; dx = dx < 0 ? -dx : dx;
          int dy = (rr & 31) - cy; dy = dy < 0 ? -dy : dy;
          float p = exp2f(fmaf(s[g][nb][r], SCALE2_, lut[dx * 32 + dy]));
          l_r[g][r] += p;
          p_sm[w * 2 + g][quad * 4 + r][nb * 16 + pcol_lo] = f2bf(p);
        }
      }
    }
    __syncthreads();  // p_sm visible

    // O += P V : wave (wq, wd): p-groups 4wq..4wq+3 x d-blocks 4wd..4wd+3
#pragma unroll
    for (int kc = 0; kc < 2; kc++) {
      bf16x8 pf[4];
#pragma unroll
      for (int g2 = 0; g2 < 4; g2++)
        pf[g2] = *(const bf16x8*)&p_sm[wq * 4 + g2][l15][kc * 32 + quad * 8];
#pragma unroll
      for (int j = 0; j < 4; j++) {
        int db = wd * 4 + j;
        int f = (db * 2 + (l15 >> 3)) & 7;
        int colb = ((kc * 4 + quad) ^ f) << 3;
        bf16x8 vf = *(const bf16x8*)&vt[db * 16 + l15][colb];
#pragma unroll
        for (int g2 = 0; g2 < 4; g2++)
          accO[g2][j] = __builtin_amdgcn_mfma_f32_16x16x32_bf16(pf[g2], vf, accO[g2][j], 0, 0, 0);
      }
    }
  }
  // l: reduce over 16 lanes, publish per 128 rows
#pragma unroll
  for (int g = 0; g < 2; g++) {
#pragma unroll
    for (int r = 0; r < 4; r++) {
#pragma unroll
      for (int off = 8; off; off >>= 1) l_r[g][r] += __shfl_xor(l_r[g][r], off, 16);
    }
  }
  if (l15 == 0) {
#pragma unroll
    for (int g = 0; g < 2; g++)
#pragma unroll
      for (int r = 0; r < 4; r++) l_sm[w * 32 + g * 16 + quad * 4 + r] = l_r[g][r];
  }
  __syncthreads();
  // epilogue
#pragma unroll
  for (int g2 = 0; g2 < 4; g2++) {
#pragma unroll
    for (int r = 0; r < 4; r++) {
      int row128 = (wq * 4 + g2) * 16 + quad * 4 + r;
      float inv = 1.f / l_sm[row128];
      int row = qb * 128 + row128;
      size_t obase = ((size_t)b * NSEQ + row) * DH_ + h * DD_;
#pragma unroll
      for (int j = 0; j < 4; j++)
        attn_out[obase + (wd * 4 + j) * 16 + l15] = f2bf(accO[g2][j][r] * inv);
    }
  }
}

extern "C" void kernel_launch(void* const* d_in, const int* in_sizes, int n_in,
                              void* d_out, int out_size, void* d_ws, size_t ws_size,
                              hipStream_t stream) {
  const float* x      = (const float*)d_in[0];
  const float* gamma  = (const float*)d_in[1];
  const float* beta   = (const float*)d_in[2];
  const float* qkv_w  = (const float*)d_in[3];
  const float* qkv_b  = (const float*)d_in[4];
  const float* proj_w = (const float*)d_in[5];
  const float* proj_b = (const float*)d_in[6];
  const float* ab     = (const float*)d_in[7];

  char* ws = (char*)d_ws;
  unsigned short* xn      = (unsigned short*)(ws);                          // 16 MiB @0
  unsigned short* wqkv    = (unsigned short*)(ws + (size_t)16 * 1048576);   //  3 MiB @16
  unsigned short* wproj   = (unsigned short*)(ws + (size_t)19 * 1048576);   //  2 MiB @19
  unsigned short* qkv     = (unsigned short*)(ws + (size_t)21 * 1048576);   // 96 MiB @21
  unsigned short* attnout = (unsigned short*)(ws + (size_t)117 * 1048576);  // 64 MiB @117
  float* out = (float*)d_out;                                               // fp32 output

  cvt_kernel<<<dim3(6144), dim3(256), 0, stream>>>(qkv_w, wqkv, 3072 * 512);
  cvt_kernel<<<dim3(4096), dim3(256), 0, stream>>>(proj_w, wproj, 512 * 2048);
  ln_kernel<<<dim3(16384), dim3(256), 0, stream>>>(x, gamma, beta, xn);
  gemm_gll<unsigned short><<<dim3(24, 128), dim3(256), 0, stream>>>(xn, 512, wqkv, 512, qkv_b, qkv, 3072, 512);
  attn_kernel<<<dim3(256, 8), dim3(256), 0, stream>>>(qkv, ab, attnout);
  gemm_gll<float><<<dim3(4, 128), dim3(256), 0, stream>>>(attnout, 2048, wproj, 2048, proj_b, out, 512, 2048);
}